// Round 5
// baseline (1586.657 us; speedup 1.0000x reference)
//
#include <hip/hip_runtime.h>
#include <stdint.h>

#define S 16384
#define D 4096
#define NE 64
#define CAP 320
#define RPW 16             // rows per wave
#define WVB 2              // waves per block
#define ROWS_B (RPW * WVB) // 32 rows per block
#define KB 64              // K chunk of W staged in LDS
#define K2ROWS 128
#define NB (S / K2ROWS)    // 128

__device__ __forceinline__ uint32_t rotl32(uint32_t v, int n) {
  return (v << n) | (v >> (32 - n));
}

// Bit-exact jax threefry for jax.random.uniform(jax.random.key(1), (S,), f32)
// under jax_threefry_partitionable=True (default since JAX 0.5.0):
//   counts = iota(u64, S); pair = (hi32=0, lo32=i); key = (0, 1)
//   bits[i] = out0 ^ out1   (32-bit path XORs the two threefry2x32 outputs)
__device__ uint32_t threefry_bits(int i) {
  const uint32_t k0 = 0u, k1 = 1u;
  const uint32_t ks2 = k0 ^ k1 ^ 0x1BD11BDAu;
  uint32_t x0 = 0u + k0;            // counts_hi + key0
  uint32_t x1 = (uint32_t)i + k1;   // counts_lo + key1
#define TFR(R) { x0 += x1; x1 = rotl32(x1, R); x1 ^= x0; }
  TFR(13) TFR(15) TFR(26) TFR(6)
  x0 += k1;  x1 += ks2 + 1u;
  TFR(17) TFR(29) TFR(16) TFR(24)
  x0 += ks2; x1 += k0 + 2u;
  TFR(13) TFR(15) TFR(26) TFR(6)
  x0 += k0;  x1 += k1 + 3u;
  TFR(17) TFR(29) TFR(16) TFR(24)
  x0 += k1;  x1 += ks2 + 4u;
  TFR(13) TFR(15) TFR(26) TFR(6)
  x0 += ks2; x1 += k0 + 5u;
#undef TFR
  return x0 ^ x1;
}

// ---- K1 fused: logits GEMM + softmax + top-2 + RNG, one kernel.
// Partition: lane = expert (64 lanes = 64 experts), each wave owns RPW=16
// rows. x addresses are wave-uniform -> scalar (s_load) path, zero LDS cost;
// only W is staged in LDS ([64][KB+1], pad-1: read bank = (lane+k)%32,
// conflict-free). Per 4-k step/wave: 4 ds_read_b32 (~23 cyc, per-CU pipe) vs
// 16x4 FMA = 128 VALU cyc (per-SIMD) -> VALU-bound (R4's 4x4 LDS tile was
// 3x LDS-throughput-bound: 2 ds_read_b128/kk fed only 16 FMAs).
// Logits finish in lane=expert layout -> softmax/top2/RNG fused here.
__global__ __launch_bounds__(128, 1) void k1_fused(const float* __restrict__ x,
                                                   const float* __restrict__ Wg,
                                                   int* __restrict__ E1, int* __restrict__ E2,
                                                   int* __restrict__ WANT,
                                                   float* __restrict__ G1, float* __restrict__ G2) {
  __shared__ float wsm[NE][KB + 1];  // 64 x 65 floats = 16.6 KB
  const int t = threadIdx.x;
  const int lane = t & 63;                                  // = expert
  const int wv = __builtin_amdgcn_readfirstlane(t >> 6);    // force uniform
  const int rowBase = blockIdx.x * ROWS_B + wv * RPW;

  const float* xrow[RPW];
#pragma unroll
  for (int r = 0; r < RPW; ++r) xrow[r] = x + (size_t)(rowBase + r) * D;

  float acc[RPW];
#pragma unroll
  for (int r = 0; r < RPW; ++r) acc[r] = 0.0f;

  for (int kb = 0; kb < D; kb += KB) {
    // ---- stage W[0:64][kb:kb+KB] -> LDS (coalesced: 16 consecutive lanes
    // cover 256 B of one expert row) ----
#pragma unroll
    for (int p = 0; p < 8; ++p) {
      const int lin = p * 128 + t;
      const int e = lin >> 4;
      const int q = lin & 15;
      const float4 w4 = *(const float4*)&Wg[(size_t)e * D + kb + 4 * q];
      wsm[e][4 * q + 0] = w4.x;
      wsm[e][4 * q + 1] = w4.y;
      wsm[e][4 * q + 2] = w4.z;
      wsm[e][4 * q + 3] = w4.w;
    }
    __syncthreads();
    // ---- compute: per 4k, 4 conflict-free b32 (W) + 16 uniform x float4 ----
#pragma unroll 4
    for (int kk = 0; kk < KB; kk += 4) {
      const float w0 = wsm[lane][kk + 0];
      const float w1 = wsm[lane][kk + 1];
      const float w2 = wsm[lane][kk + 2];
      const float w3 = wsm[lane][kk + 3];
#pragma unroll
      for (int r = 0; r < RPW; ++r) {
        const float4 xv = *(const float4*)(xrow[r] + kb + kk);
        acc[r] = fmaf(xv.w, w3, fmaf(xv.z, w2, fmaf(xv.y, w1, fmaf(xv.x, w0, acc[r]))));
      }
    }
    __syncthreads();
  }

  // ---- fused epilogue: per row, softmax + top-2 (lower-index tie-break) + RNG
#pragma unroll
  for (int r = 0; r < RPW; ++r) {
    const float l = acc[r];
    float m = l;
#pragma unroll
    for (int off = 32; off; off >>= 1) m = fmaxf(m, __shfl_xor(m, off));
    const float ex = expf(l - m);
    float ssum = ex;
#pragma unroll
    for (int off = 32; off; off >>= 1) ssum += __shfl_xor(ssum, off);
    ssum = __shfl(ssum, 0);            // single denominator like the reference
    const float gate = ex / ssum;

    float v = gate; int id = lane;
#pragma unroll
    for (int off = 32; off; off >>= 1) {
      const float vo = __shfl_xor(v, off); const int io = __shfl_xor(id, off);
      if (vo > v || (vo == v && io < id)) { v = vo; id = io; }
    }
    const float g1 = v; const int e1 = id;
    const float gate2 = (lane == e1) ? -1.0f : gate;
    v = gate2; id = lane;
#pragma unroll
    for (int off = 32; off; off >>= 1) {
      const float vo = __shfl_xor(v, off); const int io = __shfl_xor(id, off);
      if (vo > v || (vo == v && io < id)) { v = vo; id = io; }
    }
    const float g2 = v; const int e2 = id;

    if (lane == 0) {
      const int row = rowBase + r;
      const float denom = g1 + g2;
      const float g1n = g1 / denom;
      const float g2n = g2 / denom;
      const uint32_t bits = threefry_bits(row);
      const float rnd = __uint_as_float((bits >> 9) | 0x3f800000u) - 1.0f;
      E1[row] = e1; E2[row] = e2;
      WANT[row] = (rnd < 2.0f * g2n) ? 1 : 0;
      G1[row] = g1n; G2[row] = g2n;
    }
  }
}

// ---- K2: per-block (128 rows) local ranks + histograms for both streams.
__global__ __launch_bounds__(K2ROWS) void k2_rank(const int* __restrict__ E1,
                                                  const int* __restrict__ E2,
                                                  const int* __restrict__ WANT,
                                                  int* __restrict__ LR1, int* __restrict__ LR2,
                                                  int* __restrict__ H1, int* __restrict__ H2) {
  __shared__ unsigned char s1[K2ROWS], s2[K2ROWS];
  __shared__ int h1[NE], h2[NE];
  const int b = blockIdx.x, t = threadIdx.x;
  const int r = b * K2ROWS + t;
  if (t < NE) { h1[t] = 0; h2[t] = 0; }
  const int e1 = E1[r];
  const int e2 = WANT[r] ? E2[r] : NE;  // sentinel = excluded
  s1[t] = (unsigned char)e1;
  s2[t] = (unsigned char)e2;
  __syncthreads();
  int r1 = 0, r2 = 0;
  for (int j = 0; j < t; ++j) {
    r1 += (s1[j] == e1);
    r2 += (s2[j] == e2);
  }
  LR1[r] = r1; LR2[r] = r2;
  atomicAdd(&h1[e1], 1);
  if (e2 < NE) atomicAdd(&h2[e2], 1);
  __syncthreads();
  if (t < NE) { H1[b * NE + t] = h1[t]; H2[b * NE + t] = h2[t]; }
}

// ---- K3: exclusive prefix over blocks per expert + counts1 -> remaining cap2.
__global__ void k3_prefix(const int* __restrict__ H1, const int* __restrict__ H2,
                          int* __restrict__ OFF1, int* __restrict__ OFF2,
                          int* __restrict__ REM2) {
  const int e = threadIdx.x;  // 64 threads
  int run1 = 0, run2 = 0;
  for (int b = 0; b < NB; ++b) {
    OFF1[b * NE + e] = run1; run1 += H1[b * NE + e];
    OFF2[b * NE + e] = run2; run2 += H2[b * NE + e];
  }
  REM2[e] = CAP - min(run1, CAP);
}

// ---- K4: apply capacity decisions, scatter into (pre-zeroed) combine.
__global__ __launch_bounds__(256) void k4_scatter(const int* __restrict__ E1,
                                                  const int* __restrict__ E2,
                                                  const int* __restrict__ WANT,
                                                  const float* __restrict__ G1,
                                                  const float* __restrict__ G2,
                                                  const int* __restrict__ LR1,
                                                  const int* __restrict__ LR2,
                                                  const int* __restrict__ OFF1,
                                                  const int* __restrict__ OFF2,
                                                  const int* __restrict__ REM2,
                                                  float* __restrict__ out) {
  const int r = blockIdx.x * 256 + threadIdx.x;
  const int b = r / K2ROWS;
  const int e1 = E1[r];
  const int pos1 = OFF1[b * NE + e1] + LR1[r] + 1;
  if (pos1 <= CAP) out[(size_t)r * NE + e1] = G1[r];
  if (WANT[r]) {
    const int e2 = E2[r];
    const int pos2 = OFF2[b * NE + e2] + LR2[r] + 1;
    if (pos2 <= REM2[e2]) out[(size_t)r * NE + e2] = G2[r];
  }
}

extern "C" void kernel_launch(void* const* d_in, const int* in_sizes, int n_in,
                              void* d_out, int out_size, void* d_ws, size_t ws_size,
                              hipStream_t stream) {
  const float* x  = (const float*)d_in[0];
  const float* Wg = (const float*)d_in[1];
  float* out = (float*)d_out;
  char* ws = (char*)d_ws;

  size_t off = 0;
  int*   E1   = (int*)(ws + off);   off += (size_t)S * 4;
  int*   E2   = (int*)(ws + off);   off += (size_t)S * 4;
  int*   WANT = (int*)(ws + off);   off += (size_t)S * 4;
  float* G1   = (float*)(ws + off); off += (size_t)S * 4;
  float* G2   = (float*)(ws + off); off += (size_t)S * 4;
  int*   LR1  = (int*)(ws + off);   off += (size_t)S * 4;
  int*   LR2  = (int*)(ws + off);   off += (size_t)S * 4;
  int*   H1   = (int*)(ws + off);   off += (size_t)NB * NE * 4;
  int*   H2   = (int*)(ws + off);   off += (size_t)NB * NE * 4;
  int*   OFF1 = (int*)(ws + off);   off += (size_t)NB * NE * 4;
  int*   OFF2 = (int*)(ws + off);   off += (size_t)NB * NE * 4;
  int*   REM2 = (int*)(ws + off);   off += (size_t)NE * 4;

  hipMemsetAsync(d_out, 0, (size_t)out_size * sizeof(float), stream);
  k1_fused<<<S / ROWS_B, 128, 0, stream>>>(x, Wg, E1, E2, WANT, G1, G2);
  k2_rank<<<NB, K2ROWS, 0, stream>>>(E1, E2, WANT, LR1, LR2, H1, H2);
  k3_prefix<<<1, NE, 0, stream>>>(H1, H2, OFF1, OFF2, REM2);
  k4_scatter<<<S / 256, 256, 0, stream>>>(E1, E2, WANT, G1, G2, LR1, LR2, OFF1, OFF2, REM2, out);
}